// Round 2
// baseline (901.275 us; speedup 1.0000x reference)
//
#include <hip/hip_runtime.h>
#include <cstdint>
#include <cstddef>

// FlowNet-C correlation, MI355X fp32 — round 5.
// B=8 C=256 H=64 W=96, PAD=MAXD=20, K=1, S1=1, S2=2 -> 441 output channels.
// out[b, dy*21+dx, y, x] = (1/256) * sum_c in1[b,c,y,x] * in2[b,c,y+2(dy-10), x+2(dx-10)]
//
// R4 post-mortem: acc[21][8]=168 + wf 48 needed ~240 VGPR, compiler allocated 128
// -> accumulator spilled to scratch every iteration (VALUBusy 17.6% = bare FMA
// floor, nothing else busy, 466us). Fix: size the tile to provably fit.
//
// R5: 8x * 11dx per thread (two dx-groups, dx0 = 0 / 10; the overlapping dx=10
// is computed bitwise-identically by both -> benign duplicate store).
//  - acc as float2[11][4] (88 VGPR) accumulated with vector ops -> v_pk_fma_f32
//    (the packed path is how MI355X reaches its 157 TF fp32 spec; halves issue).
//  - in1 straight from global (address shared by the 21 dy-threads -> L1
//    broadcast); LDS holds only the in2 stripe: 21 rows x 29 f4, CH=2,
//    double-buffered = 38.9 KB -> 3 blocks/CU, 12 waves/CU (launch_bounds 256,3
//    caps VGPR at 170 and tells the allocator 3 waves/SIMD is the target).
//  - LDS floats/MAC = 28/88 = 0.318 (was 0.5 in the 452us kernel).
//  - stride 29 (odd): read bank-group (5*dy+2*tx+c)%8, near-uniform 8-9/group.
//  - dx0 in {0,10} keeps every window float4-aligned (s0 = 2*dx0-20 = -20 / 0),
//    so no runtime offset indexing (rule: dynamic ext-vector indexing = scratch).

typedef float v2 __attribute__((ext_vector_type(2)));

constexpr int B_ = 8, C_ = 256, H_ = 64, W_ = 96;
constexpr int D_ = 21;               // displacement grid width (per axis)
constexpr int NDX = 11;              // dx per thread (both groups compute 11)
constexpr int TX = 12;               // x-tiles (8 floats) per row
constexpr int THREADS = 256;
constexpr int NACT = D_ * TX;        // 252 compute threads
constexpr int R4U = 29;              // stripe row stride in float4 (116 floats), odd
constexpr int ROWS = D_;             // in2 rows per channel (y2 = y+2r-20, r=0..20)
constexpr int JS4 = ROWS * R4U;      // 609 f4 per channel
constexpr int CH = 2;                // channels per buffer
constexpr int BUF4 = CH * JS4;       // 1218 f4 per buffer (19.5 KB)
constexpr int NSLOT = CH * ROWS * 24;// 1008 interior f4 staging slots

__global__ __launch_bounds__(THREADS, 3) void corr_fp32(
    const float* __restrict__ in1,
    const float* __restrict__ in2,
    float* __restrict__ out)
{
    __shared__ float4 s2[2 * BUF4];  // 38976 B

    const int id  = blockIdx.x;
    const int b   = id & 7;          // b fastest -> each XCD streams one batch
    const int t   = id >> 3;
    const int dxg = t & 1;           // dx-group pair adjacent -> shared L2 window
    const int y   = t >> 1;          // y-major -> 39/41-row window reuse in L2
    const int tid = threadIdx.x;

    const int dy  = tid / TX;
    const int tx  = tid - dy * TX;
    const bool act = tid < NACT;
    const int b0  = dxg ? 0 : 5;     // interior f4 base in row (s0 = -20 or 0)

    // ---- staging descriptors: 1008 slots in 4 rounds of 256 ----
    const float* gbase = in2 + (size_t)b * C_ * H_ * W_;
    int goff[4];
    int l2i[4];                      // -1 = inactive (pad slot or OOB row)
    #pragma unroll
    for (int it = 0; it < 4; ++it) {
        int s   = tid + it * THREADS;
        bool ok = s < NSLOT;
        int sc  = ok ? s : 0;
        int j   = sc / (ROWS * 24);
        int rem = sc - j * (ROWS * 24);
        int r   = rem / 24;
        int u4  = rem - r * 24;                  // x2 chunk: x2 = 4*u4
        int y2  = y + 2 * r - 20;
        ok = ok && (y2 >= 0) && (y2 < H_);
        goff[it] = (j * H_ + (ok ? y2 : 0)) * W_ + 4 * u4;
        l2i[it]  = ok ? ((j * ROWS + r) * R4U + b0 + u4) : -1;
    }
    float4 rg[4];
    auto stage_load = [&]() {
        #pragma unroll
        for (int it = 0; it < 4; ++it) {
            if (l2i[it] >= 0) rg[it] = *(const float4*)(gbase + goff[it]);
            goff[it] += CH * H_ * W_;
        }
    };

    // ---- prologue: issue ch{0,1}, zero LDS (pads + OOB rows stay 0 forever) ----
    stage_load();
    for (int u = tid; u < 2 * BUF4; u += THREADS)
        s2[u] = float4{0.f, 0.f, 0.f, 0.f};
    __syncthreads();
    #pragma unroll
    for (int it = 0; it < 4; ++it)
        if (l2i[it] >= 0) s2[l2i[it]] = rg[it];
    __syncthreads();

    // ---- compute bases ----
    const int rbase = dy * R4U + 2 * tx;         // f4 index of thread's window
    const float4* p1 =
        (const float4*)(in1 + ((size_t)(b * C_) * H_ + y) * W_ + 8 * tx);

    v2 acc[NDX][4];
    #pragma unroll
    for (int k = 0; k < NDX; ++k)
        #pragma unroll
        for (int p = 0; p < 4; ++p) acc[k][p] = v2{0.f, 0.f};

    int rb = 0;
    for (int cc = 0; cc < C_; cc += CH) {
        const bool more = (cc + CH) < C_;
        if (more) stage_load();                  // next 2 channels in flight

        if (act) {
            #pragma unroll
            for (int j = 0; j < CH; ++j) {
                float4 a0 = p1[0];               // in1 via global/L1 broadcast
                float4 a1 = p1[1];
                p1 += (H_ * W_) / 4;
                v2 af[4] = {v2{a0.x, a0.y}, v2{a0.z, a0.w},
                            v2{a1.x, a1.y}, v2{a1.z, a1.w}};
                const float4* wp = &s2[rb + j * JS4 + rbase];
                v2 wf[14];                       // rel floats 8tx + 2m, m=0..13
                #pragma unroll
                for (int c = 0; c < 7; ++c) {
                    float4 w = wp[c];
                    wf[2 * c]     = v2{w.x, w.y};
                    wf[2 * c + 1] = v2{w.z, w.w};
                }
                // x = 8tx+2p+{0,1}; x2 = x+2k+s0 -> wf[k+p]  (v_pk_fma_f32)
                #pragma unroll
                for (int k = 0; k < NDX; ++k)
                    #pragma unroll
                    for (int p = 0; p < 4; ++p)
                        acc[k][p] += af[p] * wf[k + p];
            }
        }

        const int wb = BUF4 - rb;
        if (more) {
            #pragma unroll
            for (int it = 0; it < 4; ++it)
                if (l2i[it] >= 0) s2[wb + l2i[it]] = rg[it];
        }
        __syncthreads();
        rb = wb;
    }

    // ---- epilogue: 11 dx channels * 8 x, scaled by 1/256 ----
    if (act) {
        const float sc = 1.0f / 256.0f;
        const int dx0 = dxg * 10;
        float* po = out +
            ((size_t)(b * (D_ * D_) + dy * D_ + dx0) * H_ + y) * W_ + 8 * tx;
        #pragma unroll
        for (int k = 0; k < NDX; ++k) {
            float4 o0{acc[k][0].x * sc, acc[k][0].y * sc,
                      acc[k][1].x * sc, acc[k][1].y * sc};
            float4 o1{acc[k][2].x * sc, acc[k][2].y * sc,
                      acc[k][3].x * sc, acc[k][3].y * sc};
            ((float4*)po)[0] = o0;
            ((float4*)po)[1] = o1;
            po += (size_t)H_ * W_;               // next dx output channel
        }
    }
}

extern "C" void kernel_launch(void* const* d_in, const int* in_sizes, int n_in,
                              void* d_out, int out_size, void* d_ws, size_t ws_size,
                              hipStream_t stream) {
    const float* in1 = (const float*)d_in[0];
    const float* in2 = (const float*)d_in[1];
    float* out = (float*)d_out;
    (void)in_sizes; (void)n_in; (void)d_ws; (void)ws_size; (void)out_size;
    dim3 grid(B_ * H_ * 2);            // 1024 blocks: (b fastest, dxg, then y)
    corr_fp32<<<grid, dim3(THREADS), 0, stream>>>(in1, in2, out);
}

// Round 3
// 586.138 us; speedup vs baseline: 1.5376x; 1.5376x over previous
//
#include <hip/hip_runtime.h>
#include <cstdint>
#include <cstddef>

// FlowNet-C correlation, MI355X fp32 — round 6.
// B=8 C=256 H=64 W=96, PAD=MAXD=20, K=1, S1=1, S2=2 -> 441 output channels.
// out[b, dy*21+dx, y, x] = (1/256) * sum_c in1[b,c,y,x] * in2[b,c,y+2(dy-10), x+2(dx-10)]
//
// R4/R5 post-mortem: any per-thread tile >~100 floats gets scratch-spilled by
// this compiler regardless of launch_bounds budget (R5: VGPR_Count=72 < the 88
// acc floats, WRITE_SIZE 126->220 MB of spill leakage, VALUBusy 11.7%). Closed.
//
// R3 (452us, verified) re-analysis: LDS-READ-PORT bound: 57.3k wave ds_read_b128
// per CU x ~9.4-13.4 cyc = 270-380us of port time vs 366us dispatch. Conflicts
// only 12% over the 8-phase floor (odd f4 stride already balances banks).
// => cut LDS bytes, keep R3's register footprint exactly.
//
// R6 = R3 core (acc[8][8], 128 thr, CH=4, NROW=3, 164-float rows) plus:
//  - a (in1) straight from global: deletes s1 and 2 of 8 ds_read_b128/channel
//    (-25% LDS port). in1 row shared by 5-6 lanes at identical addresses and by
//    7 dyg-blocks -> L1/L2 broadcast.
//  - double-buffered s2, split staging: global loads issued BEFORE compute,
//    ds_writes after, ONE barrier per chunk (R3 exposed the full global latency
//    between its two barriers every chunk).

constexpr int B_ = 8, C_ = 256, H_ = 64, W_ = 96;
constexpr int D_ = 21;               // displacement grid width (per axis)
constexpr int CH = 4;                // channels staged per chunk
constexpr int NROW = 3;              // dy values per block
constexpr int NDYG = 7;              // dy groups (7*3 = 21)
constexpr int RF = 41;               // s2 row stride in float4 (164 floats, odd f4)
constexpr int THREADS = 128;
constexpr int NSLOT = CH * NROW * 24;        // 288 interior f4 staging slots
constexpr int BUF4 = CH * NROW * RF;         // 492 f4 per buffer

__global__ __launch_bounds__(THREADS, 3) void corr_fp32(
    const float* __restrict__ in1,
    const float* __restrict__ in2,
    float* __restrict__ out)
{
    __shared__ float4 s2[2 * BUF4];          // 15744 B

    const int id  = blockIdx.x;
    const int b   = id & 7;          // b fastest -> XCD round-robin over batches
    const int s   = id >> 3;
    const int y   = s / NDYG;        // y-major -> in2 window L2-resident
    const int dyg = s - y * NDYG;
    const int tid = threadIdx.x;

    // ---- compute mapping (as R3): thread = (dyj, tdx, tx), 8x * 8dx tile ----
    const int dyj  = tid / 36;               // 0..2 valid
    const int tile = tid - dyj * 36;
    const int tx   = tile % 12;
    const int tdx  = tile / 12;
    const bool act = (tid < NROW * 36);      // 108 compute threads

    // ---- staging descriptors: 288 slots in 3 rounds of 128 ----
    const float* gbase = in2 + (size_t)b * C_ * H_ * W_;
    int goff[3];
    int l2i[3];                              // -1 = pad slot or OOB row
    #pragma unroll
    for (int it = 0; it < 3; ++it) {
        int u   = tid + it * THREADS;
        bool ok = u < NSLOT;
        int uc  = ok ? u : 0;
        int j   = uc / (NROW * 24);
        int v   = uc - j * (NROW * 24);
        int r   = v / 24;
        int q   = v - r * 24;                // interior f4 chunk, x2 = 4q
        int y2  = y + 2 * (dyg * NROW + r) - 20;
        ok = ok && (y2 >= 0) && (y2 < H_);
        goff[it] = (j * H_ + (ok ? y2 : 0)) * W_ + 4 * q;
        l2i[it]  = ok ? ((j * NROW + r) * RF + 5 + q) : -1;
    }
    float4 rg[3];
    auto stage_load = [&]() {
        #pragma unroll
        for (int it = 0; it < 3; ++it) {
            if (l2i[it] >= 0) rg[it] = *(const float4*)(gbase + goff[it]);
            goff[it] += CH * H_ * W_;        // advance CH channels
        }
    };

    // ---- chunk 0 loads in flight while we zero-fill ----
    stage_load();

    // pads: 17 f4 per row (cols 0..4 and 29..40), both buffers
    for (int u = tid; u < 2 * CH * NROW * 17; u += THREADS) {
        int bb = u / (CH * NROW * 17);
        int v  = u - bb * (CH * NROW * 17);
        int row = v / 17;
        int p   = v - row * 17;
        int col = (p < 5) ? p : (p + 24);
        s2[bb * BUF4 + row * RF + col] = float4{0.f, 0.f, 0.f, 0.f};
    }
    // interiors of OOB rows stay zero forever (staging skips them)
    for (int u = tid; u < NSLOT; u += THREADS) {
        int j = u / (NROW * 24);
        int v = u - j * (NROW * 24);
        int r = v / 24;
        int q = v - r * 24;
        int y2 = y + 2 * (dyg * NROW + r) - 20;
        if (y2 < 0 || y2 >= H_) {
            int idx = (j * NROW + r) * RF + 5 + q;
            s2[idx]        = float4{0.f, 0.f, 0.f, 0.f};
            s2[BUF4 + idx] = float4{0.f, 0.f, 0.f, 0.f};
        }
    }
    // chunk 0 -> buf0 (disjoint from fills; one barrier covers both)
    #pragma unroll
    for (int it = 0; it < 3; ++it)
        if (l2i[it] >= 0) s2[l2i[it]] = rg[it];
    __syncthreads();

    // ---- per-thread compute bases ----
    const int x0  = 8 * tx;
    const int wo  = 8 * tx + 16 * tdx;       // window base float within row
    const float4* p1 =
        (const float4*)(in1 + ((size_t)(b * C_) * H_ + y) * W_) + 2 * tx;

    float acc[8][8];
    #pragma unroll
    for (int k = 0; k < 8; ++k)
        #pragma unroll
        for (int i = 0; i < 8; ++i) acc[k][i] = 0.f;

    int cur = 0;
    for (int cc = 0; cc < C_; cc += CH) {
        const bool more = (cc + CH) < C_;
        if (more) stage_load();              // next chunk in flight over compute

        if (act) {
            #pragma unroll
            for (int j = 0; j < CH; ++j) {
                float a[8];
                *(float4*)&a[0] = p1[0];     // in1 via global/L1 broadcast
                *(float4*)&a[4] = p1[1];
                p1 += (H_ * W_) / 4;         // next channel
                const float* brow =
                    (const float*)&s2[cur * BUF4 + (j * NROW + dyj) * RF] + wo;
                float w[24];
                #pragma unroll
                for (int q = 0; q < 6; ++q)
                    *(float4*)&w[4 * q] = *(const float4*)&brow[4 * q];
                #pragma unroll
                for (int k = 0; k < 8; ++k)
                    #pragma unroll
                    for (int i = 0; i < 8; ++i)
                        acc[k][i] = fmaf(a[i], w[i + 2 * k], acc[k][i]);
            }
        }

        const int nxt = cur ^ 1;
        if (more) {
            #pragma unroll
            for (int it = 0; it < 3; ++it)
                if (l2i[it] >= 0) s2[nxt * BUF4 + l2i[it]] = rg[it];
        }
        __syncthreads();                     // one barrier per chunk
        cur = nxt;
    }

    // ---- epilogue: 8 dx * 8 x per thread, scaled by 1/256 ----
    if (act) {
        const int dy  = dyg * NROW + dyj;
        const int dx0 = 8 * tdx;
        const float sc = 1.0f / 256.0f;
        #pragma unroll
        for (int k = 0; k < 8; ++k) {
            int dx = dx0 + k;
            if (dx < D_) {
                int d = dy * D_ + dx;
                float* po = out + ((size_t)(b * (D_ * D_) + d) * H_ + y) * W_ + x0;
                float4 v0{acc[k][0] * sc, acc[k][1] * sc, acc[k][2] * sc, acc[k][3] * sc};
                float4 v1{acc[k][4] * sc, acc[k][5] * sc, acc[k][6] * sc, acc[k][7] * sc};
                ((float4*)po)[0] = v0;
                ((float4*)po)[1] = v1;
            }
        }
    }
}

extern "C" void kernel_launch(void* const* d_in, const int* in_sizes, int n_in,
                              void* d_out, int out_size, void* d_ws, size_t ws_size,
                              hipStream_t stream) {
    const float* in1 = (const float*)d_in[0];
    const float* in2 = (const float*)d_in[1];
    float* out = (float*)d_out;
    (void)in_sizes; (void)n_in; (void)d_ws; (void)ws_size; (void)out_size;
    dim3 grid(B_ * H_ * NDYG);       // 3584 blocks: (b fastest, then dyg, then y)
    corr_fp32<<<grid, dim3(THREADS), 0, stream>>>(in1, in2, out);
}